// Round 4
// baseline (752.681 us; speedup 1.0000x reference)
//
#include <hip/hip_runtime.h>

typedef _Float16 half8 __attribute__((ext_vector_type(8)));
typedef float    float4v __attribute__((ext_vector_type(4)));

#define NQ 8
#define KCODES 4096
#define DIMS 128
#define BATCH 8
#define SEQ 4096
#define ROWS (BATCH*SEQ)            // 32768
#define TM 64                       // rows per block
#define NBLK (ROWS/TM)              // 512
#define NTHREADS 512                // 8 waves: 4 waves/SIMD at 2 blocks/CU
#define RESPAD 132                  // res row stride (floats), 16B-aligned
#define CANDROW 131                 // cand row stride (uints): 128 entries + pad (131%32=3, odd)
#define OUT_ELEMS (BATCH*DIMS*SEQ)  // 4194304
#define IDX_ELEMS (BATCH*SEQ*NQ)    // 262144
#define LOSS_DIV (1.0f/33554432.0f) // 1/(Q*B*N*D)
#define FRAG_HALVES ((size_t)NQ*4*256*64*8)   // hi-only f16 frags: 4.19M = 8 MB
#define SBIAS 384.0f                // key bias: keys = dot - csq/2 + 384, in ~[240,450] > 0
#define WIN 2.0f                    // refine window (>> 2*(f16 err + 0.125 pack trunc))

__device__ __forceinline__ unsigned umax_(unsigned a, unsigned b){ return a>b?a:b; }
__device__ __forceinline__ unsigned umin_(unsigned a, unsigned b){ return a<b?a:b; }

// ---------------- prep: csq[q][k] = sum_d cb^2 ; cinit = 384 - csq/2 ----------------
__global__ void prep_csq(const float* __restrict__ cb, float* __restrict__ csq,
                         float* __restrict__ cinit) {
    int c = blockIdx.x * 256 + threadIdx.x;   // q*4096+k
    const float4* p = (const float4*)(cb + (size_t)c * DIMS);
    float s = 0.f;
#pragma unroll
    for (int i = 0; i < 32; ++i) {
        float4 v = p[i];
        s += v.x * v.x + v.y * v.y + v.z * v.z + v.w * v.w;
    }
    csq[c] = s;
    cinit[c] = SBIAS - 0.5f * s;
}

// ---------------- prep: codebook -> f16 hi MFMA B-fragments (screen only) ----------------
// mfma_f32_16x16x32_f16 B-operand: lane l holds B[k=(l>>4)*8+j][n=l&15], j=0..7.
// Storage: frag g = ((q*4+kb)*256+nt)*64+lane at bhi + g*8 halves.
__global__ void prep_frags(const float* __restrict__ cb, _Float16* __restrict__ bhi,
                           float* __restrict__ loss_accum) {
    int g = blockIdx.x * 256 + threadIdx.x;   // 524288 total
    if (g == 0) loss_accum[0] = 0.f;
    int lane = g & 63;
    int nt   = (g >> 6) & 255;
    int kb   = (g >> 14) & 3;
    int q    = g >> 16;
    int code = nt * 16 + (lane & 15);
    int k0   = kb * 32 + ((lane >> 4) * 8);
    const float* src = cb + ((size_t)q * KCODES + code) * DIMS + k0;
    float4 v0 = *(const float4*)(src);
    float4 v1 = *(const float4*)(src + 4);
    half8 h;
    h[0] = (_Float16)v0.x; h[1] = (_Float16)v0.y; h[2] = (_Float16)v0.z; h[3] = (_Float16)v0.w;
    h[4] = (_Float16)v1.x; h[5] = (_Float16)v1.y; h[6] = (_Float16)v1.z; h[7] = (_Float16)v1.w;
    *(half8*)(bhi + (size_t)g * 8) = h;
}

// ---------------- main RVQ kernel ----------------
__device__ __forceinline__ void load_b(const _Float16* __restrict__ bq,
                                       const float* __restrict__ cinq,
                                       int nt, int lane, half8 (&bh)[4], float& cs) {
#pragma unroll
    for (int kb = 0; kb < 4; ++kb) {
        size_t off = (((size_t)kb * 256 + nt) * 64 + lane) * 8;
        bh[kb] = *(const half8*)(bq + off);
    }
    cs = cinq[nt * 16 + (lane & 15)];
}

// 1-pass hh screen: acc = hh-dot + (384 - csq/2). Pack approx key with idx in
// low 12 mantissa bits (keys positive -> uint order == float order), then pure
// umin/umax best-2 insert: 4 VALU ops/key, no index bookkeeping in the hot loop.
__device__ __forceinline__ void compute_tile(int nt, int lane,
        const half8 (&ahi)[4][4], const half8 (&bh)[4], float cs,
        unsigned (&p1)[4][4], unsigned (&p2)[4][4]) {
    float4v acc[4];
#pragma unroll
    for (int mt = 0; mt < 4; ++mt) { acc[mt][0] = cs; acc[mt][1] = cs; acc[mt][2] = cs; acc[mt][3] = cs; }
    __builtin_amdgcn_s_setprio(1);
#pragma unroll
    for (int kb = 0; kb < 4; ++kb)
#pragma unroll
        for (int mt = 0; mt < 4; ++mt)
            acc[mt] = __builtin_amdgcn_mfma_f32_16x16x32_f16(ahi[mt][kb], bh[kb], acc[mt], 0, 0, 0);
    __builtin_amdgcn_s_setprio(0);
    unsigned idxv = (unsigned)(nt * 16 + (lane & 15));
#pragma unroll
    for (int mt = 0; mt < 4; ++mt)
#pragma unroll
        for (int r = 0; r < 4; ++r) {
            unsigned p  = (__float_as_uint(acc[mt][r]) & 0xFFFFF000u) | idxv;  // v_and_or_b32
            unsigned t1 = umin_(p1[mt][r], p);
            p1[mt][r]   = umax_(p1[mt][r], p);
            p2[mt][r]   = umax_(p2[mt][r], t1);
        }
}

// (512,2): guarantee only 1 block/CU (generous VGPR cap 256 — tight caps
// trigger the spill cliff seen in round 2). Natural alloc ~120 <= 128 lets
// HW fit 2 blocks/CU = 16 waves/CU = 4 waves/SIMD (grid 512 = 2 blocks/CU).
__launch_bounds__(NTHREADS, 2)
__global__ void rvq_main(const float* __restrict__ x, const float* __restrict__ cb,
                         const _Float16* __restrict__ bhi,
                         const float* __restrict__ csq, const float* __restrict__ cinit,
                         float* __restrict__ out, float* __restrict__ loss_accum) {
    __shared__ float    res[TM][RESPAD];    // residual, row-major fp32 (33792 B)
    __shared__ unsigned cand[TM][CANDROW];  // packed screen candidates (33544 B)
    __shared__ float    fbin[TM];           // final best idx per row
    __shared__ float    red[NTHREADS];
    // static LDS ~= 69.6 KB -> 2 blocks/CU

    int tid  = threadIdx.x;
    int lane = tid & 63;
    int wv   = tid >> 6;                // 0..7
    int r0   = blockIdx.x * TM;
    int b    = r0 >> 12;                // / SEQ
    int n0   = r0 & (SEQ - 1);
    const float* xb = x + (size_t)b * DIMS * SEQ + n0;

    // load x[b][d][n0..n0+63] into res[n][d]: 4 threads per d, 16 floats each
    {
        int d = tid >> 2, quarter = (tid & 3) * 16;
        const float* src = xb + (size_t)d * SEQ + quarter;
#pragma unroll
        for (int t4 = 0; t4 < 4; ++t4) {
            float4 v = *(const float4*)(src + t4 * 4);
            res[quarter + t4 * 4 + 0][d] = v.x;
            res[quarter + t4 * 4 + 1][d] = v.y;
            res[quarter + t4 * 4 + 2][d] = v.z;
            res[quarter + t4 * 4 + 3][d] = v.w;
        }
    }

    float lossacc = 0.f;

    for (int q = 0; q < NQ; ++q) {
        __syncthreads();   // res stable

        // build A fragments (hi only — screen pass); per-wave, all 64 rows
        half8 ahi[4][4];
#pragma unroll
        for (int mt = 0; mt < 4; ++mt)
#pragma unroll
        for (int kb = 0; kb < 4; ++kb) {
            int row = mt * 16 + (lane & 15);
            int k0  = kb * 32 + (lane >> 4) * 8;
            float4 v0 = *(const float4*)&res[row][k0];
            float4 v1 = *(const float4*)&res[row][k0 + 4];
            half8 h;
            h[0] = (_Float16)v0.x; h[1] = (_Float16)v0.y; h[2] = (_Float16)v0.z; h[3] = (_Float16)v0.w;
            h[4] = (_Float16)v1.x; h[5] = (_Float16)v1.y; h[6] = (_Float16)v1.z; h[7] = (_Float16)v1.w;
            ahi[mt][kb] = h;
        }

        const _Float16* bq   = bhi + (size_t)q * (4 * 256 * 64 * 8);
        const float*    cinq = cinit + q * KCODES;
        const float*    csqq = csq + q * KCODES;

        unsigned p1[4][4], p2[4][4];
#pragma unroll
        for (int mt = 0; mt < 4; ++mt)
#pragma unroll
        for (int r = 0; r < 4; ++r) { p1[mt][r] = 0u; p2[mt][r] = 0u; }

        // each of 8 waves owns n-tiles [wv*32, wv*32+32); double-buffered B prefetch
        int ntBase = wv * 32;
        half8 bh0[4], bh1[4];
        float cs0, cs1;
        load_b(bq, cinq, ntBase, lane, bh0, cs0);

        // Phase stagger: odd waves burn 12 throwaway MFMAs (~one VALU-phase) so
        // their MFMA phase anti-aligns with even waves' VALU phase.
        if (wv & 1) {
            float4v accD[4];
#pragma unroll
            for (int mt = 0; mt < 4; ++mt) { accD[mt][0] = cs0; accD[mt][1] = cs0; accD[mt][2] = cs0; accD[mt][3] = cs0; }
            __builtin_amdgcn_s_setprio(1);
#pragma unroll
            for (int kb = 0; kb < 3; ++kb)
#pragma unroll
                for (int mt = 0; mt < 4; ++mt)
                    accD[mt] = __builtin_amdgcn_mfma_f32_16x16x32_f16(ahi[mt][kb], bh0[kb], accD[mt], 0, 0, 0);
            __builtin_amdgcn_s_setprio(0);
            lossacc = fmaf(0.0f, (accD[0][0] + accD[1][0]) + (accD[2][0] + accD[3][0]), lossacc);
        }

        for (int i = 0; i < 32; i += 2) {
            load_b(bq, cinq, ntBase + i + 1, lane, bh1, cs1);
            compute_tile(ntBase + i, lane, ahi, bh0, cs0, p1, p2);
            load_b(bq, cinq, ntBase + ((i + 2) & 31), lane, bh0, cs0);
            compute_tile(ntBase + i + 1, lane, ahi, bh1, cs1, p1, p2);
        }

        // pair-merge best-2 across (lane, lane^1) and write top-2-of-64 slices.
        // Sorted pairs A,B: n1=max(a1,b1); n2=max(min(a1,b1), max(a2,b2)).
#pragma unroll
        for (int mt = 0; mt < 4; ++mt)
#pragma unroll
        for (int r = 0; r < 4; ++r) {
            unsigned a1 = p1[mt][r], a2 = p2[mt][r];
            unsigned b1 = (unsigned)__shfl_xor((int)a1, 1, 64);
            unsigned b2 = (unsigned)__shfl_xor((int)a2, 1, 64);
            unsigned n1 = umax_(a1, b1);
            unsigned n2 = umax_(umin_(a1, b1), umax_(a2, b2));
            if ((lane & 1) == 0) {
                int row = mt * 16 + (lane >> 4) * 4 + r;
                int col = wv * 16 + ((lane & 15) >> 1) * 2;
                cand[row][col]     = n1;
                cand[row][col + 1] = n2;
            }
        }
        __syncthreads();

        // exact f32 refine: 8 threads per row scan 16 entries each (128 total);
        // all entries within WIN of the row max get an exact f32 dot.
        {
            int row = tid >> 3, s = tid & 7;
            const unsigned* cp = &cand[row][s * 16];
            unsigned m = 0;
#pragma unroll
            for (int k = 0; k < 16; ++k) m = umax_(m, cp[k]);
            m = umax_(m, (unsigned)__shfl_xor((int)m, 1, 64));
            m = umax_(m, (unsigned)__shfl_xor((int)m, 2, 64));
            m = umax_(m, (unsigned)__shfl_xor((int)m, 4, 64));
            float thr = __uint_as_float(m) - WIN;
            float bk = -3.4e38f;
            int   bi = KCODES;
            const float4* rv = (const float4*)&res[row][0];
            for (int k = 0; k < 16; ++k) {
                unsigned e = cp[k];
                if (__uint_as_float(e) >= thr) {
                    int idx = (int)(e & 0xFFFu);
                    const float4* cv = (const float4*)(cb + ((size_t)q * KCODES + idx) * DIMS);
                    float acc = 0.f;
#pragma unroll
                    for (int j = 0; j < 32; ++j) {
                        float4 c4 = cv[j];
                        float4 r4 = rv[j];
                        acc = fmaf(r4.x, c4.x, acc);
                        acc = fmaf(r4.y, c4.y, acc);
                        acc = fmaf(r4.z, c4.z, acc);
                        acc = fmaf(r4.w, c4.w, acc);
                    }
                    float key = acc - 0.5f * csqq[idx];
                    if (key > bk || (key == bk && idx < bi)) { bk = key; bi = idx; }
                }
            }
#pragma unroll
            for (int mask = 1; mask <= 4; mask <<= 1) {
                float ok = __shfl_xor(bk, mask, 64);
                int   oi = __shfl_xor(bi, mask, 64);
                if (ok > bk || (ok == bk && oi < bi)) { bk = ok; bi = oi; }
            }
            if (s == 0) {
                fbin[row] = (float)bi;
                out[OUT_ELEMS + (size_t)(r0 + row) * NQ + q] = (float)bi;  // index output
            }
        }
        __syncthreads();

        // residual update + commitment-loss: 8 threads/row, contiguous 16-float chunks
        {
            int row = tid >> 3, j = tid & 7;
            int bi = (int)fbin[row];
            const float* cv = cb + ((size_t)q * KCODES + bi) * DIMS + j * 16;
            float* rp = &res[row][j * 16];
#pragma unroll
            for (int t = 0; t < 4; ++t) {
                float4 c4 = *(const float4*)(cv + t * 4);
                float4 r4 = *(const float4*)(rp + t * 4);
                r4.x -= c4.x; lossacc = fmaf(r4.x, r4.x, lossacc);
                r4.y -= c4.y; lossacc = fmaf(r4.y, r4.y, lossacc);
                r4.z -= c4.z; lossacc = fmaf(r4.z, r4.z, lossacc);
                r4.w -= c4.w; lossacc = fmaf(r4.w, r4.w, lossacc);
                *(float4*)(rp + t * 4) = r4;
            }
        }
    }

    // loss reduction
    __syncthreads();
    red[tid] = lossacc;
    __syncthreads();
    for (int s = NTHREADS / 2; s > 0; s >>= 1) {
        if (tid < s) red[tid] += red[tid + s];
        __syncthreads();
    }
    if (tid == 0) atomicAdd(loss_accum, red[0]);

    // quantized output: out = x - final_residual
    {
        int d = tid >> 2, quarter = (tid & 3) * 16;
        const float* src = xb + (size_t)d * SEQ + quarter;
        float* dst = out + (size_t)b * DIMS * SEQ + (size_t)d * SEQ + n0 + quarter;
#pragma unroll
        for (int t4 = 0; t4 < 4; ++t4) {
            float4 v = *(const float4*)(src + t4 * 4);
            v.x -= res[quarter + t4 * 4 + 0][d];
            v.y -= res[quarter + t4 * 4 + 1][d];
            v.z -= res[quarter + t4 * 4 + 2][d];
            v.w -= res[quarter + t4 * 4 + 3][d];
            *(float4*)(dst + t4 * 4) = v;
        }
    }
}

__global__ void finish_loss(const float* __restrict__ loss_accum, float* __restrict__ out) {
    out[OUT_ELEMS + IDX_ELEMS] = loss_accum[0] * LOSS_DIV;
}

extern "C" void kernel_launch(void* const* d_in, const int* in_sizes, int n_in,
                              void* d_out, int out_size, void* d_ws, size_t ws_size,
                              hipStream_t stream) {
    const float* x  = (const float*)d_in[0];
    const float* cb = (const float*)d_in[1];
    float* out = (float*)d_out;
    char*  ws  = (char*)d_ws;

    float*     loss_accum = (float*)ws;
    float*     csq   = (float*)(ws + 256);
    float*     cinit = (float*)(ws + 256 + 131072);
    _Float16*  bhi   = (_Float16*)(ws + 256 + 262144);

    hipLaunchKernelGGL(prep_csq,   dim3(128),  dim3(256), 0, stream, cb, csq, cinit);
    hipLaunchKernelGGL(prep_frags, dim3(2048), dim3(256), 0, stream, cb, bhi, loss_accum);
    hipLaunchKernelGGL(rvq_main,   dim3(NBLK), dim3(NTHREADS), 0, stream,
                       x, cb, bhi, csq, cinit, out, loss_accum);
    hipLaunchKernelGGL(finish_loss, dim3(1), dim3(1), 0, stream, loss_accum, out);
}

// Round 5
// 546.819 us; speedup vs baseline: 1.3765x; 1.3765x over previous
//
#include <hip/hip_runtime.h>

typedef _Float16 half8 __attribute__((ext_vector_type(8)));
typedef float    float4v __attribute__((ext_vector_type(4)));

#define NQ 8
#define KCODES 4096
#define DIMS 128
#define BATCH 8
#define SEQ 4096
#define ROWS (BATCH*SEQ)            // 32768
#define TM 32                       // rows per block
#define NBLK (ROWS/TM)              // 1024 = 4 blocks/CU
#define NTHREADS 256
#define RESPAD 132                  // res row stride (floats), 16B-aligned
#define CANDROW 67                  // cand row stride (uints): 64 entries + pad (67%32=3)
#define OUT_ELEMS (BATCH*DIMS*SEQ)  // 4194304
#define IDX_ELEMS (BATCH*SEQ*NQ)    // 262144
#define LOSS_DIV (1.0f/33554432.0f) // 1/(Q*B*N*D)
#define FRAG_HALVES ((size_t)NQ*4*256*64*8)   // hi-only f16 frags: 4.19M = 8 MB
#define SBIAS 384.0f                // key bias: keys = dot - csq/2 + 384, in ~[240,450] > 0
#define WIN 2.0f                    // refine window (>> 2*(f16 err + 0.125 pack trunc))

__device__ __forceinline__ unsigned umax_(unsigned a, unsigned b){ return a>b?a:b; }
__device__ __forceinline__ unsigned umin_(unsigned a, unsigned b){ return a<b?a:b; }

// ---------------- prep: csq[q][k] = sum_d cb^2 ; cinit = 384 - csq/2 ----------------
__global__ void prep_csq(const float* __restrict__ cb, float* __restrict__ csq,
                         float* __restrict__ cinit) {
    int c = blockIdx.x * 256 + threadIdx.x;   // q*4096+k
    const float4* p = (const float4*)(cb + (size_t)c * DIMS);
    float s = 0.f;
#pragma unroll
    for (int i = 0; i < 32; ++i) {
        float4 v = p[i];
        s += v.x * v.x + v.y * v.y + v.z * v.z + v.w * v.w;
    }
    csq[c] = s;
    cinit[c] = SBIAS - 0.5f * s;
}

// ---------------- prep: codebook -> f16 hi MFMA B-fragments (screen only) ----------------
// mfma_f32_16x16x32_f16 B-operand: lane l holds B[k=(l>>4)*8+j][n=l&15], j=0..7.
// Storage: frag g = ((q*4+kb)*256+nt)*64+lane at bhi + g*8 halves.
__global__ void prep_frags(const float* __restrict__ cb, _Float16* __restrict__ bhi,
                           float* __restrict__ loss_accum) {
    int g = blockIdx.x * 256 + threadIdx.x;   // 524288 total
    if (g == 0) loss_accum[0] = 0.f;
    int lane = g & 63;
    int nt   = (g >> 6) & 255;
    int kb   = (g >> 14) & 3;
    int q    = g >> 16;
    int code = nt * 16 + (lane & 15);
    int k0   = kb * 32 + ((lane >> 4) * 8);
    const float* src = cb + ((size_t)q * KCODES + code) * DIMS + k0;
    float4 v0 = *(const float4*)(src);
    float4 v1 = *(const float4*)(src + 4);
    half8 h;
    h[0] = (_Float16)v0.x; h[1] = (_Float16)v0.y; h[2] = (_Float16)v0.z; h[3] = (_Float16)v0.w;
    h[4] = (_Float16)v1.x; h[5] = (_Float16)v1.y; h[6] = (_Float16)v1.z; h[7] = (_Float16)v1.w;
    *(half8*)(bhi + (size_t)g * 8) = h;
}

// ---------------- main RVQ kernel ----------------
__device__ __forceinline__ void load_b(const _Float16* __restrict__ bq,
                                       const float* __restrict__ cinq,
                                       int nt, int lane, half8 (&bh)[4], float& cs) {
#pragma unroll
    for (int kb = 0; kb < 4; ++kb) {
        size_t off = (((size_t)kb * 256 + nt) * 64 + lane) * 8;
        bh[kb] = *(const half8*)(bq + off);
    }
    cs = cinq[nt * 16 + (lane & 15)];
}

// 1-pass hh screen: acc = hh-dot + (384 - csq/2). Pack approx key with idx in
// low 12 mantissa bits (keys positive -> uint order == float order), then pure
// umin/umax best-2 insert: 4 VALU ops/key, no index bookkeeping in the hot loop.
__device__ __forceinline__ void compute_tile(int nt, int lane,
        const half8 (&ahi)[2][4], const half8 (&bh)[4], float cs,
        unsigned (&p1)[2][4], unsigned (&p2)[2][4]) {
    float4v acc[2];
#pragma unroll
    for (int mt = 0; mt < 2; ++mt) { acc[mt][0] = cs; acc[mt][1] = cs; acc[mt][2] = cs; acc[mt][3] = cs; }
    __builtin_amdgcn_s_setprio(1);
#pragma unroll
    for (int kb = 0; kb < 4; ++kb)
#pragma unroll
        for (int mt = 0; mt < 2; ++mt)
            acc[mt] = __builtin_amdgcn_mfma_f32_16x16x32_f16(ahi[mt][kb], bh[kb], acc[mt], 0, 0, 0);
    __builtin_amdgcn_s_setprio(0);
    unsigned idxv = (unsigned)(nt * 16 + (lane & 15));
#pragma unroll
    for (int mt = 0; mt < 2; ++mt)
#pragma unroll
        for (int r = 0; r < 4; ++r) {
            unsigned p  = (__float_as_uint(acc[mt][r]) & 0xFFFFF000u) | idxv;  // v_and_or_b32
            unsigned t1 = umin_(p1[mt][r], p);
            p1[mt][r]   = umax_(p1[mt][r], p);
            p2[mt][r]   = umax_(p2[mt][r], t1);
        }
}

// (256,4): target 4 waves/SIMD -> VGPR cap 128. TM=32 halves the fragment
// state (ahi 32, p1/p2 16, acc 8; ~115 unified est), so 128 is a SAFE cap —
// unlike round 2's 84-vs-150 spill cliff. Grid 1024 = 4 blocks/CU; LDS
// 26.6 KB x 4 = 106 KB <= 160. => 16 waves/CU (was 8).
__launch_bounds__(NTHREADS, 4)
__global__ void rvq_main(const float* __restrict__ x, const float* __restrict__ cb,
                         const _Float16* __restrict__ bhi,
                         const float* __restrict__ csq, const float* __restrict__ cinit,
                         float* __restrict__ out, float* __restrict__ loss_accum) {
    __shared__ float    res[TM][RESPAD];    // residual, row-major fp32 (16896 B)
    __shared__ unsigned cand[TM][CANDROW];  // packed screen candidates (8576 B)
    __shared__ float    fbin[TM];           // final best idx per row
    __shared__ float    red[NTHREADS];
    // static LDS ~= 26.6 KB -> 4 blocks/CU

    int tid  = threadIdx.x;
    int lane = tid & 63;
    int wv   = tid >> 6;                // 0..3
    int r0   = blockIdx.x * TM;
    int b    = r0 >> 12;                // / SEQ
    int n0   = r0 & (SEQ - 1);
    const float* xb = x + (size_t)b * DIMS * SEQ + n0;

    // load x[b][d][n0..n0+31] into res[n][d]: 2 threads per d, 16 floats each
    {
        int d = tid >> 1, half = (tid & 1) * 16;
        const float* src = xb + (size_t)d * SEQ + half;
#pragma unroll
        for (int t4 = 0; t4 < 4; ++t4) {
            float4 v = *(const float4*)(src + t4 * 4);
            res[half + t4 * 4 + 0][d] = v.x;
            res[half + t4 * 4 + 1][d] = v.y;
            res[half + t4 * 4 + 2][d] = v.z;
            res[half + t4 * 4 + 3][d] = v.w;
        }
    }

    float lossacc = 0.f;

    for (int q = 0; q < NQ; ++q) {
        __syncthreads();   // res stable

        // build A fragments (hi only — screen pass); 32 rows -> mt 0..1
        half8 ahi[2][4];
#pragma unroll
        for (int mt = 0; mt < 2; ++mt)
#pragma unroll
        for (int kb = 0; kb < 4; ++kb) {
            int row = mt * 16 + (lane & 15);
            int k0  = kb * 32 + (lane >> 4) * 8;
            float4 v0 = *(const float4*)&res[row][k0];
            float4 v1 = *(const float4*)&res[row][k0 + 4];
            half8 h;
            h[0] = (_Float16)v0.x; h[1] = (_Float16)v0.y; h[2] = (_Float16)v0.z; h[3] = (_Float16)v0.w;
            h[4] = (_Float16)v1.x; h[5] = (_Float16)v1.y; h[6] = (_Float16)v1.z; h[7] = (_Float16)v1.w;
            ahi[mt][kb] = h;
        }

        const _Float16* bq   = bhi + (size_t)q * (4 * 256 * 64 * 8);
        const float*    cinq = cinit + q * KCODES;
        const float*    csqq = csq + q * KCODES;

        unsigned p1[2][4], p2[2][4];
#pragma unroll
        for (int mt = 0; mt < 2; ++mt)
#pragma unroll
        for (int r = 0; r < 4; ++r) { p1[mt][r] = 0u; p2[mt][r] = 0u; }

        // each of 4 waves owns n-tiles [wv*64, wv*64+64); double-buffered B prefetch
        int ntBase = wv * 64;
        half8 bh0[4], bh1[4];
        float cs0, cs1;
        load_b(bq, cinq, ntBase, lane, bh0, cs0);

        // Phase stagger: odd waves burn 6 throwaway MFMAs (~one VALU-phase) so
        // their MFMA phase anti-aligns with even waves' VALU phase.
        if (wv & 1) {
            float4v accD[2];
#pragma unroll
            for (int mt = 0; mt < 2; ++mt) { accD[mt][0] = cs0; accD[mt][1] = cs0; accD[mt][2] = cs0; accD[mt][3] = cs0; }
            __builtin_amdgcn_s_setprio(1);
#pragma unroll
            for (int kb = 0; kb < 3; ++kb)
#pragma unroll
                for (int mt = 0; mt < 2; ++mt)
                    accD[mt] = __builtin_amdgcn_mfma_f32_16x16x32_f16(ahi[mt][kb], bh0[kb], accD[mt], 0, 0, 0);
            __builtin_amdgcn_s_setprio(0);
            lossacc = fmaf(0.0f, accD[0][0] + accD[1][0], lossacc);
        }

        for (int i = 0; i < 64; i += 2) {
            load_b(bq, cinq, ntBase + i + 1, lane, bh1, cs1);
            compute_tile(ntBase + i, lane, ahi, bh0, cs0, p1, p2);
            load_b(bq, cinq, ntBase + ((i + 2) & 63), lane, bh0, cs0);
            compute_tile(ntBase + i + 1, lane, ahi, bh1, cs1, p1, p2);
        }

        // pair-merge best-2 across (lane, lane^1) and write top-2-of-128 slices.
        // Sorted pairs A,B: n1=max(a1,b1); n2=max(min(a1,b1), max(a2,b2)).
#pragma unroll
        for (int mt = 0; mt < 2; ++mt)
#pragma unroll
        for (int r = 0; r < 4; ++r) {
            unsigned a1 = p1[mt][r], a2 = p2[mt][r];
            unsigned b1 = (unsigned)__shfl_xor((int)a1, 1, 64);
            unsigned b2 = (unsigned)__shfl_xor((int)a2, 1, 64);
            unsigned n1 = umax_(a1, b1);
            unsigned n2 = umax_(umin_(a1, b1), umax_(a2, b2));
            if ((lane & 1) == 0) {
                int row = mt * 16 + (lane >> 4) * 4 + r;
                int col = wv * 16 + ((lane & 15) >> 1) * 2;
                cand[row][col]     = n1;
                cand[row][col + 1] = n2;
            }
        }
        __syncthreads();

        // exact f32 refine: 8 threads per row scan 8 entries each (64 total);
        // all entries within WIN of the row max get an exact f32 dot.
        {
            int row = tid >> 3, s = tid & 7;
            const unsigned* cp = &cand[row][s * 8];
            unsigned m = 0;
#pragma unroll
            for (int k = 0; k < 8; ++k) m = umax_(m, cp[k]);
            m = umax_(m, (unsigned)__shfl_xor((int)m, 1, 64));
            m = umax_(m, (unsigned)__shfl_xor((int)m, 2, 64));
            m = umax_(m, (unsigned)__shfl_xor((int)m, 4, 64));
            float thr = __uint_as_float(m) - WIN;
            float bk = -3.4e38f;
            int   bi = KCODES;
            const float4* rv = (const float4*)&res[row][0];
            for (int k = 0; k < 8; ++k) {
                unsigned e = cp[k];
                if (__uint_as_float(e) >= thr) {
                    int idx = (int)(e & 0xFFFu);
                    const float4* cv = (const float4*)(cb + ((size_t)q * KCODES + idx) * DIMS);
                    float acc = 0.f;
#pragma unroll
                    for (int j = 0; j < 32; ++j) {
                        float4 c4 = cv[j];
                        float4 r4 = rv[j];
                        acc = fmaf(r4.x, c4.x, acc);
                        acc = fmaf(r4.y, c4.y, acc);
                        acc = fmaf(r4.z, c4.z, acc);
                        acc = fmaf(r4.w, c4.w, acc);
                    }
                    float key = acc - 0.5f * csqq[idx];
                    if (key > bk || (key == bk && idx < bi)) { bk = key; bi = idx; }
                }
            }
#pragma unroll
            for (int mask = 1; mask <= 4; mask <<= 1) {
                float ok = __shfl_xor(bk, mask, 64);
                int   oi = __shfl_xor(bi, mask, 64);
                if (ok > bk || (ok == bk && oi < bi)) { bk = ok; bi = oi; }
            }
            if (s == 0) {
                fbin[row] = (float)bi;
                out[OUT_ELEMS + (size_t)(r0 + row) * NQ + q] = (float)bi;  // index output
            }
        }
        __syncthreads();

        // residual update + commitment-loss: 8 threads/row, contiguous 16-float chunks
        {
            int row = tid >> 3, j = tid & 7;
            int bi = (int)fbin[row];
            const float* cv = cb + ((size_t)q * KCODES + bi) * DIMS + j * 16;
            float* rp = &res[row][j * 16];
#pragma unroll
            for (int t = 0; t < 4; ++t) {
                float4 c4 = *(const float4*)(cv + t * 4);
                float4 r4 = *(const float4*)(rp + t * 4);
                r4.x -= c4.x; lossacc = fmaf(r4.x, r4.x, lossacc);
                r4.y -= c4.y; lossacc = fmaf(r4.y, r4.y, lossacc);
                r4.z -= c4.z; lossacc = fmaf(r4.z, r4.z, lossacc);
                r4.w -= c4.w; lossacc = fmaf(r4.w, r4.w, lossacc);
                *(float4*)(rp + t * 4) = r4;
            }
        }
    }

    // loss reduction
    __syncthreads();
    red[tid] = lossacc;
    __syncthreads();
    for (int s = NTHREADS / 2; s > 0; s >>= 1) {
        if (tid < s) red[tid] += red[tid + s];
        __syncthreads();
    }
    if (tid == 0) atomicAdd(loss_accum, red[0]);

    // quantized output: out = x - final_residual
    {
        int d = tid >> 1, half = (tid & 1) * 16;
        const float* src = xb + (size_t)d * SEQ + half;
        float* dst = out + (size_t)b * DIMS * SEQ + (size_t)d * SEQ + n0 + half;
#pragma unroll
        for (int t4 = 0; t4 < 4; ++t4) {
            float4 v = *(const float4*)(src + t4 * 4);
            v.x -= res[half + t4 * 4 + 0][d];
            v.y -= res[half + t4 * 4 + 1][d];
            v.z -= res[half + t4 * 4 + 2][d];
            v.w -= res[half + t4 * 4 + 3][d];
            *(float4*)(dst + t4 * 4) = v;
        }
    }
}

__global__ void finish_loss(const float* __restrict__ loss_accum, float* __restrict__ out) {
    out[OUT_ELEMS + IDX_ELEMS] = loss_accum[0] * LOSS_DIV;
}

extern "C" void kernel_launch(void* const* d_in, const int* in_sizes, int n_in,
                              void* d_out, int out_size, void* d_ws, size_t ws_size,
                              hipStream_t stream) {
    const float* x  = (const float*)d_in[0];
    const float* cb = (const float*)d_in[1];
    float* out = (float*)d_out;
    char*  ws  = (char*)d_ws;

    float*     loss_accum = (float*)ws;
    float*     csq   = (float*)(ws + 256);
    float*     cinit = (float*)(ws + 256 + 131072);
    _Float16*  bhi   = (_Float16*)(ws + 256 + 262144);

    hipLaunchKernelGGL(prep_csq,   dim3(128),  dim3(256), 0, stream, cb, csq, cinit);
    hipLaunchKernelGGL(prep_frags, dim3(2048), dim3(256), 0, stream, cb, bhi, loss_accum);
    hipLaunchKernelGGL(rvq_main,   dim3(NBLK), dim3(NTHREADS), 0, stream,
                       x, cb, bhi, csq, cinit, out, loss_accum);
    hipLaunchKernelGGL(finish_loss, dim3(1), dim3(1), 0, stream, loss_accum, out);
}

// Round 6
// 536.355 us; speedup vs baseline: 1.4033x; 1.0195x over previous
//
#include <hip/hip_runtime.h>

typedef _Float16 half8 __attribute__((ext_vector_type(8)));
typedef float    float4v __attribute__((ext_vector_type(4)));

#define NQ 8
#define KCODES 4096
#define DIMS 128
#define BATCH 8
#define SEQ 4096
#define ROWS (BATCH*SEQ)            // 32768
#define TM 64                       // rows per block (B-traffic = ROWS/TM * 8MB -> keep TM big)
#define NBLK (ROWS/TM)              // 512
#define RESPAD 132                  // res row stride (floats), 16B-aligned
#define CANDROW 67                  // cand row stride (uints): 64 entries + bank-spread pad
#define OUT_ELEMS (BATCH*DIMS*SEQ)  // 4194304
#define IDX_ELEMS (BATCH*SEQ*NQ)    // 262144
#define LOSS_DIV (1.0f/33554432.0f) // 1/(Q*B*N*D)
#define FRAG_HALVES ((size_t)NQ*4*256*64*8)   // hi-only f16 frags: 4.19M = 8 MB
#define SBIAS 384.0f                // key bias: keys = dot - csq/2 + 384, in ~[240,450] > 0
#define WIN 2.0f                    // refine window (>> 2*(f16 err + 0.125 pack trunc))

__device__ __forceinline__ unsigned umax_(unsigned a, unsigned b){ return a>b?a:b; }
__device__ __forceinline__ unsigned umin_(unsigned a, unsigned b){ return a<b?a:b; }

// ---------------- prep: csq[q][k] = sum_d cb^2 ; cinit = 384 - csq/2 ----------------
__global__ void prep_csq(const float* __restrict__ cb, float* __restrict__ csq,
                         float* __restrict__ cinit) {
    int c = blockIdx.x * 256 + threadIdx.x;   // q*4096+k
    const float4* p = (const float4*)(cb + (size_t)c * DIMS);
    float s = 0.f;
#pragma unroll
    for (int i = 0; i < 32; ++i) {
        float4 v = p[i];
        s += v.x * v.x + v.y * v.y + v.z * v.z + v.w * v.w;
    }
    csq[c] = s;
    cinit[c] = SBIAS - 0.5f * s;
}

// ---------------- prep: codebook -> f16 hi MFMA B-fragments (screen only) ----------------
// mfma_f32_16x16x32_f16 B-operand: lane l holds B[k=(l>>4)*8+j][n=l&15], j=0..7.
// Storage: frag g = ((q*4+kb)*256+nt)*64+lane at bhi + g*8 halves.
__global__ void prep_frags(const float* __restrict__ cb, _Float16* __restrict__ bhi,
                           float* __restrict__ loss_accum) {
    int g = blockIdx.x * 256 + threadIdx.x;   // 524288 total
    if (g == 0) loss_accum[0] = 0.f;
    int lane = g & 63;
    int nt   = (g >> 6) & 255;
    int kb   = (g >> 14) & 3;
    int q    = g >> 16;
    int code = nt * 16 + (lane & 15);
    int k0   = kb * 32 + ((lane >> 4) * 8);
    const float* src = cb + ((size_t)q * KCODES + code) * DIMS + k0;
    float4 v0 = *(const float4*)(src);
    float4 v1 = *(const float4*)(src + 4);
    half8 h;
    h[0] = (_Float16)v0.x; h[1] = (_Float16)v0.y; h[2] = (_Float16)v0.z; h[3] = (_Float16)v0.w;
    h[4] = (_Float16)v1.x; h[5] = (_Float16)v1.y; h[6] = (_Float16)v1.z; h[7] = (_Float16)v1.w;
    *(half8*)(bhi + (size_t)g * 8) = h;
}

// ---------------- main RVQ kernel ----------------
__device__ __forceinline__ void load_b(const _Float16* __restrict__ bq,
                                       const float* __restrict__ cinq,
                                       int nt, int lane, half8 (&bh)[4], float& cs) {
#pragma unroll
    for (int kb = 0; kb < 4; ++kb) {
        size_t off = (((size_t)kb * 256 + nt) * 64 + lane) * 8;
        bh[kb] = *(const half8*)(bq + off);
    }
    cs = cinq[nt * 16 + (lane & 15)];
}

// 1-pass hh screen: acc = hh-dot + (384 - csq/2). Pack approx key with idx in
// low 12 mantissa bits (keys positive -> uint order == float order), then pure
// umin/umax best-2 insert: 4 VALU ops/key, no index bookkeeping in the hot loop.
__device__ __forceinline__ void compute_tile(int nt, int lane,
        const half8 (&ahi)[4][4], const half8 (&bh)[4], float cs,
        unsigned (&p1)[4][4], unsigned (&p2)[4][4]) {
    float4v acc[4];
#pragma unroll
    for (int mt = 0; mt < 4; ++mt) { acc[mt][0] = cs; acc[mt][1] = cs; acc[mt][2] = cs; acc[mt][3] = cs; }
    __builtin_amdgcn_s_setprio(1);
#pragma unroll
    for (int kb = 0; kb < 4; ++kb)
#pragma unroll
        for (int mt = 0; mt < 4; ++mt)
            acc[mt] = __builtin_amdgcn_mfma_f32_16x16x32_f16(ahi[mt][kb], bh[kb], acc[mt], 0, 0, 0);
    __builtin_amdgcn_s_setprio(0);
    unsigned idxv = (unsigned)(nt * 16 + (lane & 15));
#pragma unroll
    for (int mt = 0; mt < 4; ++mt)
#pragma unroll
        for (int r = 0; r < 4; ++r) {
            unsigned p  = (__float_as_uint(acc[mt][r]) & 0xFFFFF000u) | idxv;  // v_and_or_b32
            unsigned t1 = umin_(p1[mt][r], p);
            p1[mt][r]   = umax_(p1[mt][r], p);
            p2[mt][r]   = umax_(p2[mt][r], t1);
        }
}

// (256,2): VGPR cap 256 — generous (natural use ~190 with PF4; tight caps
// spill, round 2). Grid 512 = 2 blocks/CU pins occupancy at 2 waves/SIMD;
// the latency fix is PF DEPTH 4 (loads issued 3 compute-phases before use,
// ~600+ cyc cover > L2 latency 200-400), not more waves (round 5: doubling
// waves at TM=32 doubled L2 traffic, net zero).
__launch_bounds__(256, 2)
__global__ void rvq_main(const float* __restrict__ x, const float* __restrict__ cb,
                         const _Float16* __restrict__ bhi,
                         const float* __restrict__ csq, const float* __restrict__ cinit,
                         float* __restrict__ out, float* __restrict__ loss_accum) {
    __shared__ float    res[TM][RESPAD];    // residual, row-major fp32 (33792 B)
    __shared__ unsigned cand[TM][CANDROW];  // packed screen candidates (17152 B)
    __shared__ float    fbin[TM];           // final best idx per row
    __shared__ float    red[256];
    // static LDS = 52224 B

    int tid  = threadIdx.x;
    int lane = tid & 63;
    int wv   = tid >> 6;
    int r0   = blockIdx.x * TM;
    int b    = r0 >> 12;                // / SEQ
    int n0   = r0 & (SEQ - 1);
    const float* xb = x + (size_t)b * DIMS * SEQ + n0;

    // load x[b][d][n0..n0+63] into res[n][d]
    {
        int d = tid >> 1, half = (tid & 1) * 32;
        const float* src = xb + (size_t)d * SEQ + half;
#pragma unroll
        for (int t4 = 0; t4 < 8; ++t4) {
            float4 v = *(const float4*)(src + t4 * 4);
            res[half + t4 * 4 + 0][d] = v.x;
            res[half + t4 * 4 + 1][d] = v.y;
            res[half + t4 * 4 + 2][d] = v.z;
            res[half + t4 * 4 + 3][d] = v.w;
        }
    }

    float lossacc = 0.f;

    for (int q = 0; q < NQ; ++q) {
        __syncthreads();   // res stable

        // build A fragments (hi only — screen pass)
        half8 ahi[4][4];
#pragma unroll
        for (int mt = 0; mt < 4; ++mt)
#pragma unroll
        for (int kb = 0; kb < 4; ++kb) {
            int row = mt * 16 + (lane & 15);
            int k0  = kb * 32 + (lane >> 4) * 8;
            float4 v0 = *(const float4*)&res[row][k0];
            float4 v1 = *(const float4*)&res[row][k0 + 4];
            half8 h;
            h[0] = (_Float16)v0.x; h[1] = (_Float16)v0.y; h[2] = (_Float16)v0.z; h[3] = (_Float16)v0.w;
            h[4] = (_Float16)v1.x; h[5] = (_Float16)v1.y; h[6] = (_Float16)v1.z; h[7] = (_Float16)v1.w;
            ahi[mt][kb] = h;
        }

        const _Float16* bq   = bhi + (size_t)q * (4 * 256 * 64 * 8);
        const float*    cinq = cinit + q * KCODES;
        const float*    csqq = csq + q * KCODES;

        unsigned p1[4][4], p2[4][4];
#pragma unroll
        for (int mt = 0; mt < 4; ++mt)
#pragma unroll
        for (int r = 0; r < 4; ++r) { p1[mt][r] = 0u; p2[mt][r] = 0u; }

        // each wave owns n-tiles [wv*64, wv*64+64); 4-deep register prefetch
        // (named buffers only — runtime-indexed arrays go to scratch).
        int ntBase = wv * 64;
        half8 bhA[4], bhB[4], bhC[4], bhD[4];
        float csA, csB, csC, csD;
        load_b(bq, cinq, ntBase + 0, lane, bhA, csA);
        load_b(bq, cinq, ntBase + 1, lane, bhB, csB);
        load_b(bq, cinq, ntBase + 2, lane, bhC, csC);

        // Phase stagger: odd waves burn 12 throwaway MFMAs (~one VALU-phase) so
        // their MFMA phase anti-aligns with even waves' VALU phase.
        if (wv & 1) {
            float4v accD[4];
#pragma unroll
            for (int mt = 0; mt < 4; ++mt) { accD[mt][0] = csA; accD[mt][1] = csA; accD[mt][2] = csA; accD[mt][3] = csA; }
            __builtin_amdgcn_s_setprio(1);
#pragma unroll
            for (int kb = 0; kb < 3; ++kb)
#pragma unroll
                for (int mt = 0; mt < 4; ++mt)
                    accD[mt] = __builtin_amdgcn_mfma_f32_16x16x32_f16(ahi[mt][kb], bhA[kb], accD[mt], 0, 0, 0);
            __builtin_amdgcn_s_setprio(0);
            lossacc = fmaf(0.0f, (accD[0][0] + accD[1][0]) + (accD[2][0] + accD[3][0]), lossacc);
        }

        for (int i = 0; i < 64; i += 4) {
            load_b(bq, cinq, ntBase + ((i + 3) & 63), lane, bhD, csD);
            compute_tile(ntBase + i, lane, ahi, bhA, csA, p1, p2);
            load_b(bq, cinq, ntBase + ((i + 4) & 63), lane, bhA, csA);
            compute_tile(ntBase + i + 1, lane, ahi, bhB, csB, p1, p2);
            load_b(bq, cinq, ntBase + ((i + 5) & 63), lane, bhB, csB);
            compute_tile(ntBase + i + 2, lane, ahi, bhC, csC, p1, p2);
            load_b(bq, cinq, ntBase + ((i + 6) & 63), lane, bhC, csC);
            compute_tile(ntBase + i + 3, lane, ahi, bhD, csD, p1, p2);
        }

        // pair-merge best-2 across (lane, lane^1) and write top-2-of-128 slices.
        // Sorted pairs A,B: n1=max(a1,b1); n2=max(min(a1,b1), max(a2,b2)).
#pragma unroll
        for (int mt = 0; mt < 4; ++mt)
#pragma unroll
        for (int r = 0; r < 4; ++r) {
            unsigned a1 = p1[mt][r], a2 = p2[mt][r];
            unsigned b1 = (unsigned)__shfl_xor((int)a1, 1, 64);
            unsigned b2 = (unsigned)__shfl_xor((int)a2, 1, 64);
            unsigned n1 = umax_(a1, b1);
            unsigned n2 = umax_(umin_(a1, b1), umax_(a2, b2));
            if ((lane & 1) == 0) {
                int row = mt * 16 + (lane >> 4) * 4 + r;
                int col = wv * 16 + ((lane & 15) >> 1) * 2;
                cand[row][col]     = n1;
                cand[row][col + 1] = n2;
            }
        }
        __syncthreads();

        // exact f32 refine: 4 threads per row scan 16 entries each; all entries
        // within WIN of the row max get an exact dot (res in LDS, cb row in L2).
        {
            int row = tid >> 2, s = tid & 3;
            const unsigned* cp = &cand[row][s * 16];
            unsigned m = 0;
#pragma unroll
            for (int k = 0; k < 16; ++k) m = umax_(m, cp[k]);
            m = umax_(m, (unsigned)__shfl_xor((int)m, 1, 64));
            m = umax_(m, (unsigned)__shfl_xor((int)m, 2, 64));
            float thr = __uint_as_float(m) - WIN;
            float bk = -3.4e38f;
            int   bi = KCODES;
            const float4* rv = (const float4*)&res[row][0];
            for (int k = 0; k < 16; ++k) {
                unsigned e = cp[k];
                if (__uint_as_float(e) >= thr) {
                    int idx = (int)(e & 0xFFFu);
                    const float4* cv = (const float4*)(cb + ((size_t)q * KCODES + idx) * DIMS);
                    float acc = 0.f;
#pragma unroll
                    for (int j = 0; j < 32; ++j) {
                        float4 c4 = cv[j];
                        float4 r4 = rv[j];
                        acc = fmaf(r4.x, c4.x, acc);
                        acc = fmaf(r4.y, c4.y, acc);
                        acc = fmaf(r4.z, c4.z, acc);
                        acc = fmaf(r4.w, c4.w, acc);
                    }
                    float key = acc - 0.5f * csqq[idx];
                    if (key > bk || (key == bk && idx < bi)) { bk = key; bi = idx; }
                }
            }
#pragma unroll
            for (int mask = 1; mask <= 2; mask <<= 1) {
                float ok = __shfl_xor(bk, mask, 64);
                int   oi = __shfl_xor(bi, mask, 64);
                if (ok > bk || (ok == bk && oi < bi)) { bk = ok; bi = oi; }
            }
            if (s == 0) {
                fbin[row] = (float)bi;
                out[OUT_ELEMS + (size_t)(r0 + row) * NQ + q] = (float)bi;  // index output
            }
        }
        __syncthreads();

        // residual update + commitment-loss accumulation.
        // Each thread owns a CONTIGUOUS 32-float (128 B) chunk: bank start
        // = 4*row + 4*t (2-way across rows = free).
        {
            int row = tid >> 2, j = tid & 3;
            int bi = (int)fbin[row];
            const float* cv = cb + ((size_t)q * KCODES + bi) * DIMS + j * 32;
            float* rp = &res[row][j * 32];
#pragma unroll
            for (int t = 0; t < 8; ++t) {
                float4 c4 = *(const float4*)(cv + t * 4);
                float4 r4 = *(const float4*)(rp + t * 4);
                r4.x -= c4.x; lossacc = fmaf(r4.x, r4.x, lossacc);
                r4.y -= c4.y; lossacc = fmaf(r4.y, r4.y, lossacc);
                r4.z -= c4.z; lossacc = fmaf(r4.z, r4.z, lossacc);
                r4.w -= c4.w; lossacc = fmaf(r4.w, r4.w, lossacc);
                *(float4*)(rp + t * 4) = r4;
            }
        }
    }

    // loss reduction
    __syncthreads();
    red[tid] = lossacc;
    __syncthreads();
    for (int s = 128; s > 0; s >>= 1) {
        if (tid < s) red[tid] += red[tid + s];
        __syncthreads();
    }
    if (tid == 0) atomicAdd(loss_accum, red[0]);

    // quantized output: out = x - final_residual
    {
        int d = tid >> 1, half = (tid & 1) * 32;
        const float* src = xb + (size_t)d * SEQ + half;
        float* dst = out + (size_t)b * DIMS * SEQ + (size_t)d * SEQ + n0 + half;
#pragma unroll
        for (int t4 = 0; t4 < 8; ++t4) {
            float4 v = *(const float4*)(src + t4 * 4);
            v.x -= res[half + t4 * 4 + 0][d];
            v.y -= res[half + t4 * 4 + 1][d];
            v.z -= res[half + t4 * 4 + 2][d];
            v.w -= res[half + t4 * 4 + 3][d];
            *(float4*)(dst + t4 * 4) = v;
        }
    }
}

__global__ void finish_loss(const float* __restrict__ loss_accum, float* __restrict__ out) {
    out[OUT_ELEMS + IDX_ELEMS] = loss_accum[0] * LOSS_DIV;
}

extern "C" void kernel_launch(void* const* d_in, const int* in_sizes, int n_in,
                              void* d_out, int out_size, void* d_ws, size_t ws_size,
                              hipStream_t stream) {
    const float* x  = (const float*)d_in[0];
    const float* cb = (const float*)d_in[1];
    float* out = (float*)d_out;
    char*  ws  = (char*)d_ws;

    float*     loss_accum = (float*)ws;
    float*     csq   = (float*)(ws + 256);
    float*     cinit = (float*)(ws + 256 + 131072);
    _Float16*  bhi   = (_Float16*)(ws + 256 + 262144);

    hipLaunchKernelGGL(prep_csq,   dim3(128),  dim3(256), 0, stream, cb, csq, cinit);
    hipLaunchKernelGGL(prep_frags, dim3(2048), dim3(256), 0, stream, cb, bhi, loss_accum);
    hipLaunchKernelGGL(rvq_main,   dim3(NBLK), dim3(256), 0, stream,
                       x, cb, bhi, csq, cinit, out, loss_accum);
    hipLaunchKernelGGL(finish_loss, dim3(1), dim3(1), 0, stream, loss_accum, out);
}